// Round 19
// baseline (610.036 us; speedup 1.0000x reference)
//
#include <hip/hip_runtime.h>

#define Bz 32
#define Tz 200
#define Rz 8192
#define Kz 409
#define KP 416
#define K2 20
#define K2P 32
#define RESTz 7783

typedef __bf16 bf16x8 __attribute__((ext_vector_type(8)));
typedef float f32x4 __attribute__((ext_vector_type(4)));

// ---------------- pad+cast f32 weight [N][Kd] -> bf16 [Npad][Kpad] ------------
__launch_bounds__(256)
__global__ void k_padcast(const float* __restrict__ src, __bf16* __restrict__ dst,
                          int N, int Kd, int Npad, int Kpad) {
    int i = blockIdx.x * 256 + threadIdx.x;
    int total = Npad * Kpad;
    if (i >= total) return;
    int r = i / Kpad, c = i - r * Kpad;
    float v = (r < N && c < Kd) ? src[(size_t)r * Kd + c] : 0.f;
    dst[i] = (__bf16)v;
}

// ---- WU = wup@wz (+bU) — 256 thr, 8 rows/block, wz staged in LDS -------------
__launch_bounds__(256)
__global__ void k_wu(const float* __restrict__ wup, const float* __restrict__ wz,
                     const float* __restrict__ b_uz, const float* __restrict__ b_up,
                     float* __restrict__ WU_f, float* __restrict__ bU,
                     __bf16* __restrict__ WU_b) {
    __shared__ float lw[Kz * K2];
    __shared__ float lb[Kz];
    const int tid = threadIdx.x;
    for (int i = tid; i < Kz * K2; i += 256) lw[i] = wz[i];
    for (int i = tid; i < Kz; i += 256) lb[i] = b_uz[i];
    __syncthreads();
    const int r = blockIdx.x * 8 + (tid >> 5);
    const int c = tid & 31;
    if (r >= 512) return;
    if (r >= Kz) {
        WU_b[(size_t)r * K2P + c] = (__bf16)0.f;
        if (c == K2) bU[r] = 0.f;
        return;
    }
    const float* row = wup + (size_t)r * Kz;
    if (c < K2) {
        float a0 = 0.f, a1 = 0.f, a2 = 0.f, a3 = 0.f;
#pragma unroll 4
        for (int j = 0; j < 408; j += 4) {
            a0 = fmaf(row[j],     lw[(j)     * K2 + c], a0);
            a1 = fmaf(row[j + 1], lw[(j + 1) * K2 + c], a1);
            a2 = fmaf(row[j + 2], lw[(j + 2) * K2 + c], a2);
            a3 = fmaf(row[j + 3], lw[(j + 3) * K2 + c], a3);
        }
        a0 = fmaf(row[408], lw[408 * K2 + c], a0);
        float acc = (a0 + a1) + (a2 + a3);
        WU_f[(size_t)r * K2 + c] = acc;
        WU_b[(size_t)r * K2P + c] = (__bf16)acc;
    } else {
        WU_b[(size_t)r * K2P + c] = (__bf16)0.f;
        if (c == K2) {
            float a0 = 0.f, a1 = 0.f, a2 = 0.f, a3 = 0.f;
#pragma unroll 4
            for (int j = 0; j < 408; j += 4) {
                a0 = fmaf(row[j], lb[j], a0);
                a1 = fmaf(row[j + 1], lb[j + 1], a1);
                a2 = fmaf(row[j + 2], lb[j + 2], a2);
                a3 = fmaf(row[j + 3], lb[j + 3], a3);
            }
            a0 = fmaf(row[408], lb[408], a0);
            bU[r] = (a0 + a1) + (a2 + a3) + b_up[r];
        }
    }
}

// ---- WR = wr@WU (+bR) — 256 thr, 8 rows/block, WU_f staged in LDS ------------
__launch_bounds__(256)
__global__ void k_wr(const float* __restrict__ wr, const float* __restrict__ b_r,
                     const float* __restrict__ WU_f, const float* __restrict__ bU,
                     __bf16* __restrict__ WR_b, float* __restrict__ bR) {
    __shared__ float lw[Kz * K2];
    __shared__ float lb[Kz];
    const int tid = threadIdx.x;
    for (int i = tid; i < Kz * K2; i += 256) lw[i] = WU_f[i];
    for (int i = tid; i < Kz; i += 256) lb[i] = bU[i];
    __syncthreads();
    const int r = blockIdx.x * 8 + (tid >> 5);
    const int c = tid & 31;
    if (r >= 7808) return;
    if (r >= RESTz) {
        WR_b[(size_t)r * K2P + c] = (__bf16)0.f;
        if (c == K2) bR[r] = 0.f;
        return;
    }
    const float* row = wr + (size_t)r * Kz;
    if (c < K2) {
        float a0 = 0.f, a1 = 0.f, a2 = 0.f, a3 = 0.f;
#pragma unroll 4
        for (int j = 0; j < 408; j += 4) {
            a0 = fmaf(row[j],     lw[(j)     * K2 + c], a0);
            a1 = fmaf(row[j + 1], lw[(j + 1) * K2 + c], a1);
            a2 = fmaf(row[j + 2], lw[(j + 2) * K2 + c], a2);
            a3 = fmaf(row[j + 3], lw[(j + 3) * K2 + c], a3);
        }
        a0 = fmaf(row[408], lw[408 * K2 + c], a0);
        WR_b[(size_t)r * K2P + c] = (__bf16)((a0 + a1) + (a2 + a3));
    } else {
        WR_b[(size_t)r * K2P + c] = (__bf16)0.f;
        if (c == K2) {
            float a0 = 0.f, a1 = 0.f, a2 = 0.f, a3 = 0.f;
#pragma unroll 4
            for (int j = 0; j < 408; j += 4) {
                a0 = fmaf(row[j], lb[j], a0);
                a1 = fmaf(row[j + 1], lb[j + 1], a1);
                a2 = fmaf(row[j + 2], lb[j + 2], a2);
                a3 = fmaf(row[j + 3], lb[j + 3], a3);
            }
            a0 = fmaf(row[408], lb[408], a0);
            bR[r] = (a0 + a1) + (a2 + a3) + b_r[r];
        }
    }
}

// ---------------- pass 1: norms, scores, border mask (f32 out) ----------------
// R14 (bit-exact, DO NOT TOUCH): XLA-GPU column-reduction emulation.
__launch_bounds__(256)
__global__ void k_stats(const float* __restrict__ x, const float* __restrict__ w_proj,
                        const float* __restrict__ b_proj,
                        float* __restrict__ invnrm, float* __restrict__ score,
                        int* __restrict__ bordany, float* __restrict__ border_out) {
    const int b = blockIdx.y;
    const int c = blockIdx.x * 256 + threadIdx.x;
    const float* xp = x + (size_t)b * Tz * Rz + c;
    float* bp = border_out + (size_t)b * Tz * Rz + c;
    float p[32];
#pragma unroll
    for (int y = 0; y < 32; ++y) p[y] = 0.f;
    int nn = 0;
    for (int k = 0; k < 7; ++k) {
        const int tbase = k * 32;
#pragma unroll
        for (int y = 0; y < 32; ++y) {
            const int t = tbase + y;
            if (t < Tz) {
                float v = xp[(size_t)t * Rz];
                bool isn = (v != v);
                nn |= isn ? 1 : 0;
                float val = isn ? 0.f : v;
                bp[(size_t)t * Rz] = isn ? 1.0f : 0.0f;
                p[y] = __fadd_rn(p[y], __fmul_rn(val, val));
            }
        }
    }
#pragma unroll
    for (int off = 16; off > 0; off >>= 1)
#pragma unroll
        for (int y = 0; y < 16; ++y)
            if (y < off) p[y] = __fadd_rn(p[y], p[y + off]);
    const float ss = p[0];
    const float nv = fmaxf(__fsqrt_rn(ss), 1e-12f);
    float q[32];
#pragma unroll
    for (int y = 0; y < 32; ++y) q[y] = 0.f;
    for (int k = 0; k < 7; ++k) {
        const int tbase = k * 32;
#pragma unroll
        for (int y = 0; y < 32; ++y) {
            const int t = tbase + y;
            if (t < Tz) {
                float v = xp[(size_t)t * Rz];
                float val = (v != v) ? 0.f : v;
                float xn = __fdiv_rn(val, nv);
                float e = __fmul_rn(xn, w_proj[t]);
                q[y] = __fadd_rn(q[y], e);
            }
        }
    }
#pragma unroll
    for (int off = 16; off > 0; off >>= 1)
#pragma unroll
        for (int y = 0; y < 16; ++y)
            if (y < off) q[y] = __fadd_rn(q[y], q[y + off]);
    float sc = __fadd_rn(q[0], b_proj[0]);
    if (nn) sc = -10000.f;
    invnrm[(size_t)b * Rz + c] = __fdiv_rn(1.0f, nv);
    score[(size_t)b * Rz + c] = sc;
    bordany[(size_t)b * Rz + c] = nn;
}

// ---- R19 top-k: 256 thr, wave-level scans, rank-sort (barrier count ~30) -----
__launch_bounds__(256)
__global__ void k_topk(const float* __restrict__ score, const int* __restrict__ bordany,
                       int* __restrict__ index_ws, int* __restrict__ rest_pos,
                       float* __restrict__ o_index) {
    const int b = blockIdx.x;
    const int tid = threadIdx.x;
    const int lane = tid & 63;
    const int wv = tid >> 6;
    __shared__ unsigned su[Rz];
    __shared__ unsigned hist[256];
    __shared__ unsigned sfx[257];
    __shared__ unsigned ckey[512];
    __shared__ unsigned cidx[512];
    __shared__ unsigned short rnk[512];
    __shared__ unsigned cnum;
    __shared__ unsigned sh_prefix;
    __shared__ int sh_need;
    __shared__ int wsum[4];

    for (int i = tid; i < Rz; i += 256) {
        unsigned u = __float_as_uint(score[(size_t)b * Rz + i]);
        u = (u & 0x80000000u) ? ~u : (u | 0x80000000u);
        su[i] = u;
    }
    if (tid == 0) { cnum = 0u; sfx[256] = 0u; }
    __syncthreads();

    unsigned prefix = 0u, pmask = 0u;
    int need = Kz;
    for (int byte = 3; byte >= 0; --byte) {
        const int sh = byte * 8;
        hist[tid] = 0u;
        __syncthreads();
        for (int i = tid; i < Rz; i += 256) {
            unsigned u = su[i];
            if ((u & pmask) == prefix) atomicAdd(&hist[(u >> sh) & 255u], 1u);
        }
        __syncthreads();
        if (tid < 64) {
            // suffix-sum over 256 buckets: 4 buckets/lane + Kogge-Stone suffix
            unsigned h0 = hist[4 * tid], h1 = hist[4 * tid + 1];
            unsigned h2 = hist[4 * tid + 2], h3 = hist[4 * tid + 3];
            unsigned t3 = h3, t2 = h2 + t3, t1 = h1 + t2, t0 = h0 + t1;
            unsigned U = t0;
#pragma unroll
            for (int off = 1; off < 64; off <<= 1) {
                unsigned u2 = __shfl_down(U, off);
                if (tid + off < 64) U += u2;
            }
            const unsigned T = U - t0;   // strictly-higher lanes
            sfx[4 * tid]     = t0 + T;
            sfx[4 * tid + 1] = t1 + T;
            sfx[4 * tid + 2] = t2 + T;
            sfx[4 * tid + 3] = t3 + T;
        }
        __syncthreads();
        {
            unsigned cur = sfx[tid], nxt = sfx[tid + 1];
            if (cur >= (unsigned)need && nxt < (unsigned)need) {
                sh_need = need - (int)nxt;
                sh_prefix = prefix | ((unsigned)tid << sh);
            }
        }
        __syncthreads();
        prefix = sh_prefix;
        need = sh_need;
        pmask |= (0xFFu << sh);
        __syncthreads();
    }
    const unsigned Tval = prefix;

    for (int i = tid; i < Rz; i += 256) {
        unsigned u = su[i];
        if (u >= Tval) {
            unsigned p = atomicAdd(&cnum, 1u);
            if (p < 512u) { ckey[p] = u; cidx[p] = (unsigned)i; }
        }
    }
    __syncthreads();
    const int cn = (cnum < 512u) ? (int)cnum : 512;

    // rank-sort: rank = #{j : key_j > key_i || (key_j == key_i && idx_j < idx_i)}
    for (int i = tid; i < cn; i += 256) {
        const unsigned ki = ckey[i], ii = cidx[i];
        int r = 0;
        for (int j = 0; j < cn; ++j) {
            const unsigned kj = ckey[j];
            r += (kj > ki || (kj == ki && cidx[j] < ii)) ? 1 : 0;
        }
        rnk[i] = (unsigned short)r;
        if (r < Kz) {
            index_ws[b * Kz + r] = (int)ii;
            o_index[(size_t)b * Kz + r] = (float)ii;
        }
    }
    __syncthreads();
    for (int i = tid; i < Rz; i += 256)
        su[i] = (bordany[(size_t)b * Rz + i] != 0) ? 1u : 0u;
    __syncthreads();
    for (int i = tid; i < cn; i += 256)
        if (rnk[i] < Kz) su[cidx[i] & 8191u] = 1u;
    __syncthreads();
    // rest positions: 32 cols/thread, wave-level inclusive scan
    int cnt = 0;
    const int base = tid * 32;
#pragma unroll
    for (int o = 0; o < 32; ++o) cnt += (su[base + o] == 0u) ? 1 : 0;
    int inc = cnt;
#pragma unroll
    for (int off = 1; off < 64; off <<= 1) {
        int v2 = __shfl_up(inc, off);
        if (lane >= off) inc += v2;
    }
    if (lane == 63) wsum[wv] = inc;
    __syncthreads();
    int woff = 0;
    for (int w = 0; w < 4; ++w)
        if (w < wv) woff += wsum[w];
    const int total_un = wsum[0] + wsum[1] + wsum[2] + wsum[3];
    int run = woff + inc - cnt;   // exclusive prefix of unoccupied
    for (int o = 0; o < 32; ++o) {
        const int c = base + o;
        const bool un = (su[c] == 0u);
        int pos = un ? run : (total_un + (c - run));
        if (un) run++;
        if (pos < RESTz) rest_pos[b * RESTz + pos] = c;
    }
}

// ---------------- gather selected, normalized columns -> bf16 [6400][KP] ------
__launch_bounds__(256)
__global__ void k_gather(const float* __restrict__ x, const float* __restrict__ invnrm,
                         const int* __restrict__ index_ws, __bf16* __restrict__ x_topk) {
    const int m = blockIdx.x;
    const int b = m / Tz;
    const float* xrow = x + (size_t)m * Rz;
    for (int kk = threadIdx.x; kk < KP; kk += 256) {
        float val = 0.f;
        if (kk < Kz) {
            const unsigned idx = (unsigned)index_ws[b * Kz + kk] & 8191u;
            float v = xrow[idx];
            if (v != v) v = 0.f;
            val = __fmul_rn(v, invnrm[(size_t)b * Rz + idx]);
        }
        x_topk[(size_t)m * KP + kk] = (__bf16)val;
    }
}

// ---------------- BatchNorm over (b,k) per t (bf16 in, bf16 out) --------------
__launch_bounds__(256)
__global__ void k_bn(const __bf16* __restrict__ h, const float* __restrict__ gamma,
                     const float* __restrict__ beta, __bf16* __restrict__ hbn) {
    const int t = blockIdx.x;
    const int tid = threadIdx.x;
    float s = 0.f, s2 = 0.f;
    for (int i = tid; i < Bz * Kz; i += 256) {
        int b = i / Kz, j = i - b * Kz;
        float v = (float)h[(size_t)(b * Tz + t) * KP + j];
        s += v;
        s2 += v * v;
    }
    for (int off = 32; off > 0; off >>= 1) {
        s += __shfl_down(s, off);
        s2 += __shfl_down(s2, off);
    }
    __shared__ float rs[4], rs2[4];
    __shared__ float sc_sh, sf_sh;
    const int wid = tid >> 6;
    if ((tid & 63) == 0) { rs[wid] = s; rs2[wid] = s2; }
    __syncthreads();
    if (tid == 0) {
        float S = rs[0] + rs[1] + rs[2] + rs[3];
        float S2 = rs2[0] + rs2[1] + rs2[2] + rs2[3];
        const float invN = 1.f / (float)(Bz * Kz);
        float mu = S * invN;
        float var = S2 * invN - mu * mu;
        float rstd = rsqrtf(var + 1e-5f);
        float scl = gamma[t] * rstd;
        sc_sh = scl;
        sf_sh = beta[t] - mu * scl;
    }
    __syncthreads();
    const float scl = sc_sh, sft = sf_sh;
    for (int i = tid; i < Bz * KP; i += 256) {
        int b = i / KP, j = i - b * KP;
        float outv = 0.f;
        if (j < Kz) {
            float v = (float)h[(size_t)(b * Tz + t) * KP + j];
            outv = v * scl + sft;
        }
        hbn[(size_t)(b * Tz + t) * KP + j] = (__bf16)outv;
    }
}

// ---------------- dense mask writer (f32): mask[b,t,r] = sel[b][r] ------------
__launch_bounds__(256)
__global__ void k_mask(const int* __restrict__ index_ws, float* __restrict__ o_mask) {
    const int bt = blockIdx.x;
    const int b = bt / Tz;
    const int tid = threadIdx.x;
    __shared__ unsigned bm[256];
    bm[tid] = 0u;
    __syncthreads();
    for (int i = tid; i < Kz; i += 256) {
        unsigned idx = (unsigned)index_ws[b * Kz + i] & 8191u;
        atomicOr(&bm[idx >> 5], 1u << (idx & 31u));
    }
    __syncthreads();
    const unsigned bits = bm[tid];
    float* dst = o_mask + (size_t)bt * Rz + tid * 32;
#pragma unroll
    for (int g = 0; g < 8; ++g) {
        float4 v;
        v.x = ((bits >> (g * 4 + 0)) & 1u) ? 1.0f : 0.0f;
        v.y = ((bits >> (g * 4 + 1)) & 1u) ? 1.0f : 0.0f;
        v.z = ((bits >> (g * 4 + 2)) & 1u) ? 1.0f : 0.0f;
        v.w = ((bits >> (g * 4 + 3)) & 1u) ? 1.0f : 0.0f;
        *(float4*)(dst + g * 4) = v;
    }
}

// ---- 128x128-tile MFMA GEMM with global_load_lds(16B) into linear LDS --------
template <int EPI>
__launch_bounds__(256)
__global__ void k_gemm(const __bf16* __restrict__ A, int lda, int ksteps,
                       const __bf16* __restrict__ Wb, int ldb,
                       const float* __restrict__ bias,
                       __bf16* __restrict__ b_out,
                       float* __restrict__ o_xc,
                       const int* __restrict__ index_ws,
                       const int* __restrict__ rest_pos,
                       float* __restrict__ o_recon) {
    __shared__ __bf16 As[128][32];
    __shared__ __bf16 Bs[128][32];
    const int m0 = blockIdx.x * 128;
    const int n0 = blockIdx.y * 128;
    const int tid = threadIdx.x;
    const int lane = tid & 63;
    const int wid = tid >> 6;
    const int wm = wid >> 1, wn = wid & 1;
    const int r0 = lane >> 2;
    const int sg = (lane & 3) * 8;
    const int fr = lane & 15;
    const int fg = lane >> 4;
    f32x4 acc[4][4];
#pragma unroll
    for (int i = 0; i < 4; ++i)
#pragma unroll
        for (int j = 0; j < 4; ++j) {
            f32x4 z = {0.f, 0.f, 0.f, 0.f};
            acc[i][j] = z;
        }

    const int ca = wid * 16 + r0;
    const int cb = (wid + 4) * 16 + r0;
    const __bf16* gA0 = A + (size_t)(m0 + ca) * lda + sg;
    const __bf16* gA1 = A + (size_t)(m0 + cb) * lda + sg;
    const __bf16* gB0 = Wb + (size_t)(n0 + ca) * ldb + sg;
    const __bf16* gB1 = Wb + (size_t)(n0 + cb) * ldb + sg;
    __bf16* lA0 = &As[wid * 16][0];
    __bf16* lA1 = &As[(wid + 4) * 16][0];
    __bf16* lB0 = &Bs[wid * 16][0];
    __bf16* lB1 = &Bs[(wid + 4) * 16][0];

    for (int s = 0; s < ksteps; ++s) {
        const int k0 = s * 32;
        __syncthreads();
        __builtin_amdgcn_global_load_lds(gA0 + k0, lA0, 16, 0, 0);
        __builtin_amdgcn_global_load_lds(gA1 + k0, lA1, 16, 0, 0);
        __builtin_amdgcn_global_load_lds(gB0 + k0, lB0, 16, 0, 0);
        __builtin_amdgcn_global_load_lds(gB1 + k0, lB1, 16, 0, 0);
        __syncthreads();
        bf16x8 af[4], bf[4];
#pragma unroll
        for (int mi = 0; mi < 4; ++mi)
            af[mi] = *(const bf16x8*)&As[wm * 64 + mi * 16 + fr][fg * 8];
#pragma unroll
        for (int ni = 0; ni < 4; ++ni)
            bf[ni] = *(const bf16x8*)&Bs[wn * 64 + ni * 16 + fr][fg * 8];
#pragma unroll
        for (int mi = 0; mi < 4; ++mi)
#pragma unroll
            for (int ni = 0; ni < 4; ++ni)
                acc[mi][ni] = __builtin_amdgcn_mfma_f32_16x16x32_bf16(af[mi], bf[ni],
                                                                      acc[mi][ni], 0, 0, 0);
    }

#pragma unroll
    for (int mi = 0; mi < 4; ++mi)
#pragma unroll
        for (int ni = 0; ni < 4; ++ni)
#pragma unroll
            for (int rr = 0; rr < 4; ++rr) {
                const int gm = m0 + wm * 64 + mi * 16 + fg * 4 + rr;
                const int gn = n0 + wn * 64 + ni * 16 + fr;
                const float v = acc[mi][ni][rr];
                if constexpr (EPI == 0) {
                    if (gn < KP) {
                        float val = (gn < Kz) ? (v + bias[gn]) : 0.f;
                        b_out[(size_t)gm * KP + gn] = (__bf16)val;
                    }
                } else if constexpr (EPI == 1) {
                    if (gn < K2P) {
                        float val = (gn < K2) ? (v + bias[gn]) : 0.f;
                        if (gn < K2) o_xc[(size_t)gm * K2 + gn] = val;
                        b_out[(size_t)gm * K2P + gn] = (__bf16)val;
                    }
                } else if constexpr (EPI == 3) {
                    if (gn < Kz) {
                        float val = v + bias[gn];
                        const int bb = gm / Tz;
                        const unsigned col = (unsigned)index_ws[bb * Kz + gn] & 8191u;
                        o_recon[(size_t)gm * Rz + col] = val;
                    }
                } else {
                    if (gn < RESTz) {
                        const float val = v + bias[gn];
                        const int bb = gm / Tz;
                        const unsigned col = (unsigned)rest_pos[bb * RESTz + gn] & 8191u;
                        o_recon[(size_t)gm * Rz + col] = val;
                    }
                }
            }
}

extern "C" void kernel_launch(void* const* d_in, const int* in_sizes, int n_in,
                              void* d_out, int out_size, void* d_ws, size_t ws_size,
                              hipStream_t stream) {
    (void)in_sizes; (void)n_in; (void)out_size;
    const float* x           = (const float*)d_in[0];
    const float* w_proj      = (const float*)d_in[1];
    const float* b_proj      = (const float*)d_in[2];
    const float* w_process   = (const float*)d_in[3];
    const float* b_process   = (const float*)d_in[4];
    const float* bn_gamma    = (const float*)d_in[5];
    const float* bn_beta     = (const float*)d_in[6];
    const float* w_compress  = (const float*)d_in[7];
    const float* b_compress  = (const float*)d_in[8];
    const float* w_unzip     = (const float*)d_in[9];
    const float* b_unzip     = (const float*)d_in[10];
    const float* w_unprocess = (const float*)d_in[11];
    const float* b_unprocess = (const float*)d_in[12];
    const float* w_rest      = (const float*)d_in[13];
    const float* b_rest      = (const float*)d_in[14];

    float* out = (float*)d_out;
    float* o_recon  = out;
    float* o_xc     = o_recon + (size_t)Bz * Tz * Rz;
    float* o_mask   = o_xc + (size_t)Bz * Tz * K2;
    float* o_border = o_mask + (size_t)Bz * Tz * Rz;
    float* o_index  = o_border + (size_t)Bz * Tz * Rz;

    const size_t SLOT = ((size_t)Bz * Tz * KP * 2 + 255) & ~(size_t)255;
    const size_t IDXB = ((size_t)Bz * Kz * 4 + 255) & ~(size_t)255;
    const size_t RESB = ((size_t)Bz * RESTz * 4 + 255) & ~(size_t)255;
    const size_t WPB  = ((size_t)512 * KP * 2 + 255) & ~(size_t)255;
    const size_t WCB  = ((size_t)128 * KP * 2 + 255) & ~(size_t)255;
    const size_t WUF  = ((size_t)Kz * K2 * 4 + 255) & ~(size_t)255;
    const size_t BUB  = ((size_t)512 * 4 + 255) & ~(size_t)255;
    const size_t WUB  = ((size_t)512 * K2P * 2 + 255) & ~(size_t)255;
    const size_t WRB  = ((size_t)7808 * K2P * 2 + 255) & ~(size_t)255;
    const size_t BRB  = ((size_t)7808 * 4 + 255) & ~(size_t)255;
    const size_t need = 3 * SLOT + IDXB + RESB + WPB + WCB + WUF + BUB + WUB + WRB + BRB;
    if (ws_size < need) return;

    char* ws = (char*)d_ws;
    size_t off = 0;
    auto AL = [&](size_t n) { void* p = ws + off; off += n; return p; };
    __bf16* S1 = (__bf16*)AL(SLOT);
    __bf16* S2 = (__bf16*)AL(SLOT);
    __bf16* S3 = (__bf16*)AL(SLOT);
    int* index_ws = (int*)AL(IDXB);
    int* rest_pos = (int*)AL(RESB);
    __bf16* wp_b  = (__bf16*)AL(WPB);
    __bf16* wc_b  = (__bf16*)AL(WCB);
    float*  WU_f  = (float*)AL(WUF);
    float*  bU    = (float*)AL(BUB);
    __bf16* WU_b  = (__bf16*)AL(WUB);
    __bf16* WR_b  = (__bf16*)AL(WRB);
    float*  bR    = (float*)AL(BRB);

    float* invnrm = (float*)S2;
    float* score  = invnrm + (size_t)Bz * Rz;
    int*   bordany = (int*)(score + (size_t)Bz * Rz);

    __bf16* x_topk = S1;
    __bf16* hbuf   = S2;
    __bf16* hbn    = S3;
    __bf16* xc_pad = S2;

    auto PC = [&](const float* src, __bf16* dst, int N, int Kd, int Npad, int Kpad) {
        int total = Npad * Kpad;
        k_padcast<<<dim3((total + 255) / 256), dim3(256), 0, stream>>>(src, dst, N, Kd, Npad, Kpad);
    };
    PC(w_process, wp_b, Kz, Kz, 512, KP);
    PC(w_compress, wc_b, K2, Kz, 128, KP);
    k_wu<<<dim3(64), dim3(256), 0, stream>>>(w_unprocess, w_unzip, b_unzip, b_unprocess,
                                             WU_f, bU, WU_b);
    k_wr<<<dim3(976), dim3(256), 0, stream>>>(w_rest, b_rest, WU_f, bU, WR_b, bR);

    k_stats<<<dim3(Rz / 256, Bz), dim3(256), 0, stream>>>(x, w_proj, b_proj, invnrm, score,
                                                          bordany, o_border);
    k_topk<<<dim3(Bz), dim3(256), 0, stream>>>(score, bordany, index_ws, rest_pos, o_index);
    k_gather<<<dim3(Bz * Tz), dim3(256), 0, stream>>>(x, invnrm, index_ws, x_topk);

    dim3 blk(256);
    k_gemm<0><<<dim3(50, 4), blk, 0, stream>>>(x_topk, KP, 13, wp_b, KP, b_process,
                                               hbuf, nullptr, nullptr, nullptr, nullptr);
    k_bn<<<dim3(Tz), blk, 0, stream>>>(hbuf, bn_gamma, bn_beta, hbn);
    k_gemm<1><<<dim3(50, 1), blk, 0, stream>>>(hbn, KP, 13, wc_b, KP, b_compress,
                                               xc_pad, o_xc, nullptr, nullptr, nullptr);
    k_gemm<3><<<dim3(50, 4), blk, 0, stream>>>(xc_pad, K2P, 1, WU_b, K2P, bU,
                                               nullptr, nullptr, index_ws, nullptr, o_recon);
    k_gemm<4><<<dim3(50, 61), blk, 0, stream>>>(xc_pad, K2P, 1, WR_b, K2P, bR,
                                                nullptr, nullptr, nullptr, rest_pos, o_recon);
    k_mask<<<dim3(Bz * Tz), dim3(256), 0, stream>>>(index_ws, o_mask);
}

// Round 20
// 494.085 us; speedup vs baseline: 1.2347x; 1.2347x over previous
//
#include <hip/hip_runtime.h>

#define Bz 32
#define Tz 200
#define Rz 8192
#define Kz 409
#define KP 416
#define K2 20
#define K2P 32
#define RESTz 7783

typedef __bf16 bf16x8 __attribute__((ext_vector_type(8)));
typedef float f32x4 __attribute__((ext_vector_type(4)));

// ---------------- pad+cast f32 weight [N][Kd] -> bf16 [Npad][Kpad] ------------
__launch_bounds__(256)
__global__ void k_padcast(const float* __restrict__ src, __bf16* __restrict__ dst,
                          int N, int Kd, int Npad, int Kpad) {
    int i = blockIdx.x * 256 + threadIdx.x;
    int total = Npad * Kpad;
    if (i >= total) return;
    int r = i / Kpad, c = i - r * Kpad;
    float v = (r < N && c < Kd) ? src[(size_t)r * Kd + c] : 0.f;
    dst[i] = (__bf16)v;
}

// ---- WU = wup@wz (+bU) — 256 thr, 8 rows/block, wz staged in LDS -------------
__launch_bounds__(256)
__global__ void k_wu(const float* __restrict__ wup, const float* __restrict__ wz,
                     const float* __restrict__ b_uz, const float* __restrict__ b_up,
                     float* __restrict__ WU_f, float* __restrict__ bU,
                     __bf16* __restrict__ WU_b) {
    __shared__ float lw[Kz * K2];
    __shared__ float lb[Kz];
    const int tid = threadIdx.x;
    for (int i = tid; i < Kz * K2; i += 256) lw[i] = wz[i];
    for (int i = tid; i < Kz; i += 256) lb[i] = b_uz[i];
    __syncthreads();
    const int r = blockIdx.x * 8 + (tid >> 5);
    const int c = tid & 31;
    if (r >= 512) return;
    if (r >= Kz) {
        WU_b[(size_t)r * K2P + c] = (__bf16)0.f;
        if (c == K2) bU[r] = 0.f;
        return;
    }
    const float* row = wup + (size_t)r * Kz;
    if (c < K2) {
        float a0 = 0.f, a1 = 0.f, a2 = 0.f, a3 = 0.f;
#pragma unroll 4
        for (int j = 0; j < 408; j += 4) {
            a0 = fmaf(row[j],     lw[(j)     * K2 + c], a0);
            a1 = fmaf(row[j + 1], lw[(j + 1) * K2 + c], a1);
            a2 = fmaf(row[j + 2], lw[(j + 2) * K2 + c], a2);
            a3 = fmaf(row[j + 3], lw[(j + 3) * K2 + c], a3);
        }
        a0 = fmaf(row[408], lw[408 * K2 + c], a0);
        float acc = (a0 + a1) + (a2 + a3);
        WU_f[(size_t)r * K2 + c] = acc;
        WU_b[(size_t)r * K2P + c] = (__bf16)acc;
    } else {
        WU_b[(size_t)r * K2P + c] = (__bf16)0.f;
        if (c == K2) {
            float a0 = 0.f, a1 = 0.f, a2 = 0.f, a3 = 0.f;
#pragma unroll 4
            for (int j = 0; j < 408; j += 4) {
                a0 = fmaf(row[j], lb[j], a0);
                a1 = fmaf(row[j + 1], lb[j + 1], a1);
                a2 = fmaf(row[j + 2], lb[j + 2], a2);
                a3 = fmaf(row[j + 3], lb[j + 3], a3);
            }
            a0 = fmaf(row[408], lb[408], a0);
            bU[r] = (a0 + a1) + (a2 + a3) + b_up[r];
        }
    }
}

// ---- WR = wr@WU (+bR) — 256 thr, 8 rows/block, WU_f staged in LDS ------------
__launch_bounds__(256)
__global__ void k_wr(const float* __restrict__ wr, const float* __restrict__ b_r,
                     const float* __restrict__ WU_f, const float* __restrict__ bU,
                     __bf16* __restrict__ WR_b, float* __restrict__ bR) {
    __shared__ float lw[Kz * K2];
    __shared__ float lb[Kz];
    const int tid = threadIdx.x;
    for (int i = tid; i < Kz * K2; i += 256) lw[i] = WU_f[i];
    for (int i = tid; i < Kz; i += 256) lb[i] = bU[i];
    __syncthreads();
    const int r = blockIdx.x * 8 + (tid >> 5);
    const int c = tid & 31;
    if (r >= 7808) return;
    if (r >= RESTz) {
        WR_b[(size_t)r * K2P + c] = (__bf16)0.f;
        if (c == K2) bR[r] = 0.f;
        return;
    }
    const float* row = wr + (size_t)r * Kz;
    if (c < K2) {
        float a0 = 0.f, a1 = 0.f, a2 = 0.f, a3 = 0.f;
#pragma unroll 4
        for (int j = 0; j < 408; j += 4) {
            a0 = fmaf(row[j],     lw[(j)     * K2 + c], a0);
            a1 = fmaf(row[j + 1], lw[(j + 1) * K2 + c], a1);
            a2 = fmaf(row[j + 2], lw[(j + 2) * K2 + c], a2);
            a3 = fmaf(row[j + 3], lw[(j + 3) * K2 + c], a3);
        }
        a0 = fmaf(row[408], lw[408 * K2 + c], a0);
        WR_b[(size_t)r * K2P + c] = (__bf16)((a0 + a1) + (a2 + a3));
    } else {
        WR_b[(size_t)r * K2P + c] = (__bf16)0.f;
        if (c == K2) {
            float a0 = 0.f, a1 = 0.f, a2 = 0.f, a3 = 0.f;
#pragma unroll 4
            for (int j = 0; j < 408; j += 4) {
                a0 = fmaf(row[j], lb[j], a0);
                a1 = fmaf(row[j + 1], lb[j + 1], a1);
                a2 = fmaf(row[j + 2], lb[j + 2], a2);
                a3 = fmaf(row[j + 3], lb[j + 3], a3);
            }
            a0 = fmaf(row[408], lb[408], a0);
            bR[r] = (a0 + a1) + (a2 + a3) + b_r[r];
        }
    }
}

// ---------------- pass 1: norms, scores, border mask (f32 out) ----------------
// R14 (bit-exact, DO NOT TOUCH): XLA-GPU column-reduction emulation.
__launch_bounds__(256)
__global__ void k_stats(const float* __restrict__ x, const float* __restrict__ w_proj,
                        const float* __restrict__ b_proj,
                        float* __restrict__ invnrm, float* __restrict__ score,
                        int* __restrict__ bordany, float* __restrict__ border_out) {
    const int b = blockIdx.y;
    const int c = blockIdx.x * 256 + threadIdx.x;
    const float* xp = x + (size_t)b * Tz * Rz + c;
    float* bp = border_out + (size_t)b * Tz * Rz + c;
    float p[32];
#pragma unroll
    for (int y = 0; y < 32; ++y) p[y] = 0.f;
    int nn = 0;
    for (int k = 0; k < 7; ++k) {
        const int tbase = k * 32;
#pragma unroll
        for (int y = 0; y < 32; ++y) {
            const int t = tbase + y;
            if (t < Tz) {
                float v = xp[(size_t)t * Rz];
                bool isn = (v != v);
                nn |= isn ? 1 : 0;
                float val = isn ? 0.f : v;
                bp[(size_t)t * Rz] = isn ? 1.0f : 0.0f;
                p[y] = __fadd_rn(p[y], __fmul_rn(val, val));
            }
        }
    }
#pragma unroll
    for (int off = 16; off > 0; off >>= 1)
#pragma unroll
        for (int y = 0; y < 16; ++y)
            if (y < off) p[y] = __fadd_rn(p[y], p[y + off]);
    const float ss = p[0];
    const float nv = fmaxf(__fsqrt_rn(ss), 1e-12f);
    float q[32];
#pragma unroll
    for (int y = 0; y < 32; ++y) q[y] = 0.f;
    for (int k = 0; k < 7; ++k) {
        const int tbase = k * 32;
#pragma unroll
        for (int y = 0; y < 32; ++y) {
            const int t = tbase + y;
            if (t < Tz) {
                float v = xp[(size_t)t * Rz];
                float val = (v != v) ? 0.f : v;
                float xn = __fdiv_rn(val, nv);
                float e = __fmul_rn(xn, w_proj[t]);
                q[y] = __fadd_rn(q[y], e);
            }
        }
    }
#pragma unroll
    for (int off = 16; off > 0; off >>= 1)
#pragma unroll
        for (int y = 0; y < 16; ++y)
            if (y < off) q[y] = __fadd_rn(q[y], q[y + off]);
    float sc = __fadd_rn(q[0], b_proj[0]);
    if (nn) sc = -10000.f;
    invnrm[(size_t)b * Rz + c] = __fdiv_rn(1.0f, nv);
    score[(size_t)b * Rz + c] = sc;
    bordany[(size_t)b * Rz + c] = nn;
}

// ---- top-k (R18 1024-thr version) + colsrc map build -------------------------
// colsrc[b][col]: 0x40000000 = selected(mask=1); 0x20000000|pos = rest-scatter;
// 0x10000000|rank = index-scatter; 0 = zero-fill. Rest has priority (matches
// reference overwrite order: at[:,index].set then at[:,rest].set).
__launch_bounds__(1024)
__global__ void k_topk(const float* __restrict__ score, const int* __restrict__ bordany,
                       int* __restrict__ index_ws, int* __restrict__ colsrc,
                       float* __restrict__ o_index) {
    const int b = blockIdx.x;
    const int tid = threadIdx.x;
    __shared__ unsigned su[Rz];
    __shared__ unsigned hist[256];
    __shared__ unsigned sfx[256];
    __shared__ unsigned ckey[512];
    __shared__ unsigned cidx[512];
    __shared__ unsigned cnum;
    __shared__ unsigned sh_prefix;
    __shared__ int sh_need;
    __shared__ int scnt[1024];

    for (int i = tid; i < Rz; i += 1024) {
        unsigned u = __float_as_uint(score[(size_t)b * Rz + i]);
        u = (u & 0x80000000u) ? ~u : (u | 0x80000000u);
        su[i] = u;
    }
    __syncthreads();

    unsigned prefix = 0u, pmask = 0u;
    int need = Kz;
    for (int byte = 3; byte >= 0; --byte) {
        const int sh = byte * 8;
        if (tid < 256) hist[tid] = 0u;
        __syncthreads();
        for (int i = tid; i < Rz; i += 1024) {
            unsigned u = su[i];
            if ((u & pmask) == prefix) atomicAdd(&hist[(u >> sh) & 255u], 1u);
        }
        __syncthreads();
        if (tid < 256) sfx[tid] = hist[tid];
        __syncthreads();
        for (int off = 1; off < 256; off <<= 1) {
            unsigned add = 0u;
            if (tid < 256 && tid + off < 256) add = sfx[tid + off];
            __syncthreads();
            if (tid < 256) sfx[tid] += add;
            __syncthreads();
        }
        if (tid < 256) {
            unsigned above = (tid == 255) ? 0u : sfx[tid + 1];
            if (sfx[tid] >= (unsigned)need && above < (unsigned)need) {
                sh_need = need - (int)above;
                sh_prefix = prefix | ((unsigned)tid << sh);
            }
        }
        __syncthreads();
        prefix = sh_prefix;
        need = sh_need;
        pmask |= (0xFFu << sh);
        __syncthreads();
    }
    const unsigned Tval = prefix;

    if (tid == 0) cnum = 0u;
    __syncthreads();
    for (int i = tid; i < Rz; i += 1024) {
        unsigned u = su[i];
        if (u >= Tval) {
            unsigned p = atomicAdd(&cnum, 1u);
            if (p < 512u) { ckey[p] = u; cidx[p] = (unsigned)i; }
        }
    }
    __syncthreads();
    const int cn = (cnum < 512u) ? (int)cnum : 512;
    for (int i = tid; i < 512; i += 1024)
        if (i >= cn) { ckey[i] = 0u; cidx[i] = 0xFFFFFFFFu; }
    __syncthreads();

    for (int kk = 2; kk <= 512; kk <<= 1) {
        for (int j = kk >> 1; j > 0; j >>= 1) {
            if (tid < 256) {
                const int i = ((tid & ~(j - 1)) << 1) | (tid & (j - 1));
                const int l = i | j;
                unsigned ka = ckey[i], kb = ckey[l];
                unsigned ia = cidx[i], ib = cidx[l];
                bool a_after_b = (ka < kb) || (ka == kb && ia > ib);
                bool b_after_a = (kb < ka) || (kb == ka && ib > ia);
                bool desc = ((i & kk) == 0);
                bool dosw = desc ? a_after_b : b_after_a;
                if (dosw) { ckey[i] = kb; ckey[l] = ka; cidx[i] = ib; cidx[l] = ia; }
            }
            __syncthreads();
        }
    }

    for (int i = tid; i < Kz; i += 1024) {
        int idx = (int)(cidx[i] & 8191u);
        index_ws[b * Kz + i] = idx;
        o_index[(size_t)b * Kz + i] = (float)idx;
    }
    __syncthreads();
    // su: 0 = unoccupied, 1 = border-occupied, 2+rank = selected
    for (int i = tid; i < Rz; i += 1024)
        su[i] = (bordany[(size_t)b * Rz + i] != 0) ? 1u : 0u;
    __syncthreads();
    for (int i = tid; i < Kz; i += 1024) su[cidx[i] & 8191u] = 2u + (unsigned)i;
    __syncthreads();
    int cnt = 0;
    {
        const int base = tid * 8;
#pragma unroll
        for (int o = 0; o < 8; ++o) cnt += (su[base + o] == 0u) ? 1 : 0;
    }
    scnt[tid] = cnt;
    __syncthreads();
    for (int offp = 1; offp < 1024; offp <<= 1) {
        int add = (tid >= offp) ? scnt[tid - offp] : 0;
        __syncthreads();
        scnt[tid] += add;
        __syncthreads();
    }
    const int total_un = scnt[1023];
    int run = scnt[tid] - cnt;
    const int base = tid * 8;
    for (int o = 0; o < 8; ++o) {
        const int c = base + o;
        const unsigned s = su[c];
        const bool un = (s == 0u);
        int pos = un ? run : (total_un + (c - run));
        if (un) run++;
        int src;
        if (pos < RESTz) src = 0x20000000 | pos;
        else if (s >= 2u) src = 0x10000000 | (int)(s - 2u);
        else src = 0;
        if (s >= 2u) src |= 0x40000000;
        colsrc[b * Rz + c] = src;
    }
}

// ---------------- gather selected, normalized columns -> bf16 [6400][KP] ------
__launch_bounds__(256)
__global__ void k_gather(const float* __restrict__ x, const float* __restrict__ invnrm,
                         const int* __restrict__ index_ws, __bf16* __restrict__ x_topk) {
    const int m = blockIdx.x;
    const int b = m / Tz;
    const float* xrow = x + (size_t)m * Rz;
    for (int kk = threadIdx.x; kk < KP; kk += 256) {
        float val = 0.f;
        if (kk < Kz) {
            const unsigned idx = (unsigned)index_ws[b * Kz + kk] & 8191u;
            float v = xrow[idx];
            if (v != v) v = 0.f;
            val = __fmul_rn(v, invnrm[(size_t)b * Rz + idx]);
        }
        x_topk[(size_t)m * KP + kk] = (__bf16)val;
    }
}

// ---------------- BatchNorm over (b,k) per t (bf16 in, bf16 out) --------------
__launch_bounds__(256)
__global__ void k_bn(const __bf16* __restrict__ h, const float* __restrict__ gamma,
                     const float* __restrict__ beta, __bf16* __restrict__ hbn) {
    const int t = blockIdx.x;
    const int tid = threadIdx.x;
    float s = 0.f, s2 = 0.f;
    for (int i = tid; i < Bz * Kz; i += 256) {
        int b = i / Kz, j = i - b * Kz;
        float v = (float)h[(size_t)(b * Tz + t) * KP + j];
        s += v;
        s2 += v * v;
    }
    for (int off = 32; off > 0; off >>= 1) {
        s += __shfl_down(s, off);
        s2 += __shfl_down(s2, off);
    }
    __shared__ float rs[4], rs2[4];
    __shared__ float sc_sh, sf_sh;
    const int wid = tid >> 6;
    if ((tid & 63) == 0) { rs[wid] = s; rs2[wid] = s2; }
    __syncthreads();
    if (tid == 0) {
        float S = rs[0] + rs[1] + rs[2] + rs[3];
        float S2 = rs2[0] + rs2[1] + rs2[2] + rs2[3];
        const float invN = 1.f / (float)(Bz * Kz);
        float mu = S * invN;
        float var = S2 * invN - mu * mu;
        float rstd = rsqrtf(var + 1e-5f);
        float scl = gamma[t] * rstd;
        sc_sh = scl;
        sf_sh = beta[t] - mu * scl;
    }
    __syncthreads();
    const float scl = sc_sh, sft = sf_sh;
    for (int i = tid; i < Bz * KP; i += 256) {
        int b = i / KP, j = i - b * KP;
        float outv = 0.f;
        if (j < Kz) {
            float v = (float)h[(size_t)(b * Tz + t) * KP + j];
            outv = v * scl + sft;
        }
        hbn[(size_t)(b * Tz + t) * KP + j] = (__bf16)outv;
    }
}

// ---- R20: fused decoder — dense recon + mask, per-column gathered weights ----
// Grid (nt=64, mt=4, b=32). Tile: 64 rows (t) x 128 cols. K=32 (one MFMA step).
__launch_bounds__(256)
__global__ void k_recon(const __bf16* __restrict__ xc, const __bf16* __restrict__ WU_b,
                        const __bf16* __restrict__ WR_b, const float* __restrict__ bU,
                        const float* __restrict__ bR, const int* __restrict__ colsrc,
                        float* __restrict__ o_recon, float* __restrict__ o_mask) {
    __shared__ __bf16 As[64][32];
    __shared__ __bf16 Bs[128][32];
    __shared__ float biasv[128];
    __shared__ float maskv[128];
    const int n0 = blockIdx.x * 128;
    const int m0 = blockIdx.y * 64;
    const int b = blockIdx.z;
    const int tid = threadIdx.x;
    const int lane = tid & 63;
    const int w = tid >> 6;
    // stage A: xc rows (t = m0..m0+63), zero-pad t >= Tz
    {
        const int row = tid >> 2, seg = (tid & 3) * 8;
        const int t = m0 + row;
        bf16x8 v = {};
        if (t < Tz) v = *(const bf16x8*)(xc + ((size_t)b * Tz + t) * K2P + seg);
        *(bf16x8*)&As[row][seg] = v;
    }
    // stage B: gather weight row per column + bias + mask
    {
        const int col = tid >> 1, half = tid & 1;
        const int s = colsrc[b * Rz + n0 + col];
        const __bf16* srcrow = nullptr;
        float bv = 0.f;
        if (s & 0x20000000) {
            const int p = s & 0xFFFF;
            srcrow = WR_b + (size_t)p * K2P;
            bv = bR[p];
        } else if (s & 0x10000000) {
            const int k = s & 0xFFFF;
            srcrow = WU_b + (size_t)k * K2P;
            bv = bU[k];
        }
        bf16x8 v0 = {}, v1 = {};
        if (srcrow) {
            v0 = *(const bf16x8*)(srcrow + half * 16);
            v1 = *(const bf16x8*)(srcrow + half * 16 + 8);
        }
        *(bf16x8*)&Bs[col][half * 16] = v0;
        *(bf16x8*)&Bs[col][half * 16 + 8] = v1;
        if (half == 0) {
            biasv[col] = bv;
            maskv[col] = (s & 0x40000000) ? 1.0f : 0.0f;
        }
    }
    __syncthreads();
    const int fr = lane & 15, fg = lane >> 4;
    bf16x8 af = *(const bf16x8*)&As[w * 16 + fr][fg * 8];
    f32x4 acc[8];
#pragma unroll
    for (int ni = 0; ni < 8; ++ni) {
        f32x4 z = {0.f, 0.f, 0.f, 0.f};
        acc[ni] = z;
    }
#pragma unroll
    for (int ni = 0; ni < 8; ++ni) {
        bf16x8 bf = *(const bf16x8*)&Bs[ni * 16 + fr][fg * 8];
        acc[ni] = __builtin_amdgcn_mfma_f32_16x16x32_bf16(af, bf, acc[ni], 0, 0, 0);
    }
#pragma unroll
    for (int ni = 0; ni < 8; ++ni)
#pragma unroll
        for (int rr = 0; rr < 4; ++rr) {
            const int t = m0 + w * 16 + fg * 4 + rr;
            if (t < Tz) {
                const int cl = ni * 16 + fr;
                const size_t o = ((size_t)(b * Tz + t)) * Rz + n0 + cl;
                o_recon[o] = acc[ni][rr] + biasv[cl];
                o_mask[o] = maskv[cl];
            }
        }
}

// ---- 128x128-tile MFMA GEMM with global_load_lds(16B) into linear LDS --------
template <int EPI>
__launch_bounds__(256)
__global__ void k_gemm(const __bf16* __restrict__ A, int lda, int ksteps,
                       const __bf16* __restrict__ Wb, int ldb,
                       const float* __restrict__ bias,
                       __bf16* __restrict__ b_out,
                       float* __restrict__ o_xc) {
    __shared__ __bf16 As[128][32];
    __shared__ __bf16 Bs[128][32];
    const int m0 = blockIdx.x * 128;
    const int n0 = blockIdx.y * 128;
    const int tid = threadIdx.x;
    const int lane = tid & 63;
    const int wid = tid >> 6;
    const int wm = wid >> 1, wn = wid & 1;
    const int r0 = lane >> 2;
    const int sg = (lane & 3) * 8;
    const int fr = lane & 15;
    const int fg = lane >> 4;
    f32x4 acc[4][4];
#pragma unroll
    for (int i = 0; i < 4; ++i)
#pragma unroll
        for (int j = 0; j < 4; ++j) {
            f32x4 z = {0.f, 0.f, 0.f, 0.f};
            acc[i][j] = z;
        }

    const int ca = wid * 16 + r0;
    const int cb = (wid + 4) * 16 + r0;
    const __bf16* gA0 = A + (size_t)(m0 + ca) * lda + sg;
    const __bf16* gA1 = A + (size_t)(m0 + cb) * lda + sg;
    const __bf16* gB0 = Wb + (size_t)(n0 + ca) * ldb + sg;
    const __bf16* gB1 = Wb + (size_t)(n0 + cb) * ldb + sg;
    __bf16* lA0 = &As[wid * 16][0];
    __bf16* lA1 = &As[(wid + 4) * 16][0];
    __bf16* lB0 = &Bs[wid * 16][0];
    __bf16* lB1 = &Bs[(wid + 4) * 16][0];

    for (int s = 0; s < ksteps; ++s) {
        const int k0 = s * 32;
        __syncthreads();
        __builtin_amdgcn_global_load_lds(gA0 + k0, lA0, 16, 0, 0);
        __builtin_amdgcn_global_load_lds(gA1 + k0, lA1, 16, 0, 0);
        __builtin_amdgcn_global_load_lds(gB0 + k0, lB0, 16, 0, 0);
        __builtin_amdgcn_global_load_lds(gB1 + k0, lB1, 16, 0, 0);
        __syncthreads();
        bf16x8 af[4], bf[4];
#pragma unroll
        for (int mi = 0; mi < 4; ++mi)
            af[mi] = *(const bf16x8*)&As[wm * 64 + mi * 16 + fr][fg * 8];
#pragma unroll
        for (int ni = 0; ni < 4; ++ni)
            bf[ni] = *(const bf16x8*)&Bs[wn * 64 + ni * 16 + fr][fg * 8];
#pragma unroll
        for (int mi = 0; mi < 4; ++mi)
#pragma unroll
            for (int ni = 0; ni < 4; ++ni)
                acc[mi][ni] = __builtin_amdgcn_mfma_f32_16x16x32_bf16(af[mi], bf[ni],
                                                                      acc[mi][ni], 0, 0, 0);
    }

#pragma unroll
    for (int mi = 0; mi < 4; ++mi)
#pragma unroll
        for (int ni = 0; ni < 4; ++ni)
#pragma unroll
            for (int rr = 0; rr < 4; ++rr) {
                const int gm = m0 + wm * 64 + mi * 16 + fg * 4 + rr;
                const int gn = n0 + wn * 64 + ni * 16 + fr;
                const float v = acc[mi][ni][rr];
                if constexpr (EPI == 0) {
                    if (gn < KP) {
                        float val = (gn < Kz) ? (v + bias[gn]) : 0.f;
                        b_out[(size_t)gm * KP + gn] = (__bf16)val;
                    }
                } else {
                    if (gn < K2P) {
                        float val = (gn < K2) ? (v + bias[gn]) : 0.f;
                        if (gn < K2) o_xc[(size_t)gm * K2 + gn] = val;
                        b_out[(size_t)gm * K2P + gn] = (__bf16)val;
                    }
                }
            }
}

extern "C" void kernel_launch(void* const* d_in, const int* in_sizes, int n_in,
                              void* d_out, int out_size, void* d_ws, size_t ws_size,
                              hipStream_t stream) {
    (void)in_sizes; (void)n_in; (void)out_size;
    const float* x           = (const float*)d_in[0];
    const float* w_proj      = (const float*)d_in[1];
    const float* b_proj      = (const float*)d_in[2];
    const float* w_process   = (const float*)d_in[3];
    const float* b_process   = (const float*)d_in[4];
    const float* bn_gamma    = (const float*)d_in[5];
    const float* bn_beta     = (const float*)d_in[6];
    const float* w_compress  = (const float*)d_in[7];
    const float* b_compress  = (const float*)d_in[8];
    const float* w_unzip     = (const float*)d_in[9];
    const float* b_unzip     = (const float*)d_in[10];
    const float* w_unprocess = (const float*)d_in[11];
    const float* b_unprocess = (const float*)d_in[12];
    const float* w_rest      = (const float*)d_in[13];
    const float* b_rest      = (const float*)d_in[14];

    float* out = (float*)d_out;
    float* o_recon  = out;
    float* o_xc     = o_recon + (size_t)Bz * Tz * Rz;
    float* o_mask   = o_xc + (size_t)Bz * Tz * K2;
    float* o_border = o_mask + (size_t)Bz * Tz * Rz;
    float* o_index  = o_border + (size_t)Bz * Tz * Rz;

    const size_t SLOT = ((size_t)Bz * Tz * KP * 2 + 255) & ~(size_t)255;
    const size_t IDXB = ((size_t)Bz * Kz * 4 + 255) & ~(size_t)255;
    const size_t CSB  = ((size_t)Bz * Rz * 4 + 255) & ~(size_t)255;    // colsrc
    const size_t WPB  = ((size_t)512 * KP * 2 + 255) & ~(size_t)255;
    const size_t WCB  = ((size_t)128 * KP * 2 + 255) & ~(size_t)255;
    const size_t WUF  = ((size_t)Kz * K2 * 4 + 255) & ~(size_t)255;
    const size_t BUB  = ((size_t)512 * 4 + 255) & ~(size_t)255;
    const size_t WUB  = ((size_t)512 * K2P * 2 + 255) & ~(size_t)255;
    const size_t WRB  = ((size_t)7808 * K2P * 2 + 255) & ~(size_t)255;
    const size_t BRB  = ((size_t)7808 * 4 + 255) & ~(size_t)255;
    const size_t need = 3 * SLOT + IDXB + CSB + WPB + WCB + WUF + BUB + WUB + WRB + BRB;
    if (ws_size < need) return;

    char* ws = (char*)d_ws;
    size_t off = 0;
    auto AL = [&](size_t n) { void* p = ws + off; off += n; return p; };
    __bf16* S1 = (__bf16*)AL(SLOT);
    __bf16* S2 = (__bf16*)AL(SLOT);
    __bf16* S3 = (__bf16*)AL(SLOT);
    int* index_ws = (int*)AL(IDXB);
    int* colsrc   = (int*)AL(CSB);
    __bf16* wp_b  = (__bf16*)AL(WPB);
    __bf16* wc_b  = (__bf16*)AL(WCB);
    float*  WU_f  = (float*)AL(WUF);
    float*  bU    = (float*)AL(BUB);
    __bf16* WU_b  = (__bf16*)AL(WUB);
    __bf16* WR_b  = (__bf16*)AL(WRB);
    float*  bR    = (float*)AL(BRB);

    float* invnrm = (float*)S2;
    float* score  = invnrm + (size_t)Bz * Rz;
    int*   bordany = (int*)(score + (size_t)Bz * Rz);

    __bf16* x_topk = S1;
    __bf16* hbuf   = S2;
    __bf16* hbn    = S3;
    __bf16* xc_pad = S2;

    auto PC = [&](const float* src, __bf16* dst, int N, int Kd, int Npad, int Kpad) {
        int total = Npad * Kpad;
        k_padcast<<<dim3((total + 255) / 256), dim3(256), 0, stream>>>(src, dst, N, Kd, Npad, Kpad);
    };
    PC(w_process, wp_b, Kz, Kz, 512, KP);
    PC(w_compress, wc_b, K2, Kz, 128, KP);
    k_wu<<<dim3(64), dim3(256), 0, stream>>>(w_unprocess, w_unzip, b_unzip, b_unprocess,
                                             WU_f, bU, WU_b);
    k_wr<<<dim3(976), dim3(256), 0, stream>>>(w_rest, b_rest, WU_f, bU, WR_b, bR);

    k_stats<<<dim3(Rz / 256, Bz), dim3(256), 0, stream>>>(x, w_proj, b_proj, invnrm, score,
                                                          bordany, o_border);
    k_topk<<<dim3(Bz), dim3(1024), 0, stream>>>(score, bordany, index_ws, colsrc, o_index);
    k_gather<<<dim3(Bz * Tz), dim3(256), 0, stream>>>(x, invnrm, index_ws, x_topk);

    dim3 blk(256);
    k_gemm<0><<<dim3(50, 4), blk, 0, stream>>>(x_topk, KP, 13, wp_b, KP, b_process,
                                               hbuf, nullptr);
    k_bn<<<dim3(Tz), blk, 0, stream>>>(hbuf, bn_gamma, bn_beta, hbn);
    k_gemm<1><<<dim3(50, 1), blk, 0, stream>>>(hbn, KP, 13, wc_b, KP, b_compress,
                                               xc_pad, o_xc);
    // fused decoder: dense recon + mask from gathered low-rank weights
    k_recon<<<dim3(64, 4, Bz), blk, 0, stream>>>(xc_pad, WU_b, WR_b, bU, bR, colsrc,
                                                 o_recon, o_mask);
}